// Round 3
// baseline (107.205 us; speedup 1.0000x reference)
//
#include <hip/hip_runtime.h>
#include <stdint.h>

// Problem: x0,y0 [B=64, C=36, L=4096] float32.
// out = y0 * (mean(x0,-1) + mean(y0,-1)), float32.
// Memory-bound: 113 MB min traffic -> ~18 us floor at 6.3 TB/s.
//
// Structure: ONE WAVE PER ROW. No __syncthreads, no LDS. Each lane:
// 16 float4 x-loads (consumed into sums) + 16 float4 y-loads (held in
// registers), shfl_xor butterfly reduce across 64 lanes, then 16
// nontemporal float4 stores. 2304 waves, fully independent.

#define LL    4096
#define ROWS  (64 * 36)   // 2304
#define WPB   4           // waves per 256-thread block
#define NV    16          // float4 chunks per lane per tensor (4096/4/64)

typedef float v4f __attribute__((ext_vector_type(4)));

__global__ __launch_bounds__(256) void spo2_waverow(
    const float* __restrict__ x,
    const float* __restrict__ y,
    float* __restrict__ out)
{
    const int wave = blockIdx.x * WPB + (threadIdx.x >> 6);
    const int lane = threadIdx.x & 63;
    const size_t base = (size_t)wave * LL;

    const float4* xv = (const float4*)(x + base);
    const float4* yv = (const float4*)(y + base);
    v4f*          ov = (v4f*)(out + base);

    float4 yr[NV];
    float s0 = 0.f, s1 = 0.f, s2 = 0.f, s3 = 0.f;
#pragma unroll
    for (int i = 0; i < NV; ++i) {
        float4 xc = xv[lane + i * 64];
        float4 yc = yv[lane + i * 64];
        yr[i] = yc;
        s0 += xc.x + xc.y;
        s1 += xc.z + xc.w;
        s2 += yc.x + yc.y;
        s3 += yc.z + yc.w;
    }
    float s = (s0 + s1) + (s2 + s3);

    // 64-lane butterfly: every lane ends with the full row sum
#pragma unroll
    for (int off = 32; off > 0; off >>= 1)
        s += __shfl_xor(s, off, 64);

    const float scale = s * (1.0f / (float)LL);

#pragma unroll
    for (int i = 0; i < NV; ++i) {
        v4f o;
        o.x = yr[i].x * scale;
        o.y = yr[i].y * scale;
        o.z = yr[i].z * scale;
        o.w = yr[i].w * scale;
        __builtin_nontemporal_store(o, &ov[lane + i * 64]);
    }
}

extern "C" void kernel_launch(void* const* d_in, const int* in_sizes, int n_in,
                              void* d_out, int out_size, void* d_ws, size_t ws_size,
                              hipStream_t stream) {
    const float* x = (const float*)d_in[0];
    const float* y = (const float*)d_in[1];
    float* out = (float*)d_out;
    spo2_waverow<<<ROWS / WPB, 256, 0, stream>>>(x, y, out);
}